// Round 9
// baseline (24657.359 us; speedup 1.0000x reference)
//
#include <hip/hip_runtime.h>

#define BB 32
#define TT 512
#define SS 1024
#define HH 512
#define MM 16

typedef float f4 __attribute__((ext_vector_type(4)));

// d_ws layout (bytes)
#define WS_SLOTS  0          // 1024 u32 (512 aslots + 512 bslots)
#define WS_CTX    4096       // 32*512 f32
#define WS_H      69632      // 2*32*512 f32
#define WS_WIHB   200704     // 2048*1024 bf16 (4 MB)
#define WS_WHHB   4395008    // 2048*512 bf16 (2 MB)
#define WS_WGB    6492160    // 48*512 bf16

#define PADR 640
#define IDXH(k) ((k) + (((k) >> 4) << 2))

__device__ __forceinline__ float sigm(float z) { return 1.f / (1.f + __expf(-z)); }
__device__ __forceinline__ float bf2f(unsigned short u) {
  return __uint_as_float((unsigned)u << 16);
}
__device__ __forceinline__ unsigned short f2bf(float f) {
  unsigned u = __float_as_uint(f);
  return (unsigned short)((u + 0x7fffu + ((u >> 16) & 1u)) >> 16);
}
__device__ __forceinline__ void fma4(float& a, const f4& u, const f4& v) {
  a = fmaf(u.x, v.x, fmaf(u.y, v.y, fmaf(u.z, v.z, fmaf(u.w, v.w, a))));
}

// LLC-coherent wide ops (bypass L1/L2)
__device__ __forceinline__ void ld1_sys(const float* p0, f4& a) {
  asm volatile("global_load_dwordx4 %0, %1, off sc1\n\ts_waitcnt vmcnt(0)"
               : "=&v"(a) : "v"(p0) : "memory");
}
__device__ __forceinline__ void st_sys(float* p, float v) {
  asm volatile("global_store_dword %0, %1, off sc1" :: "v"(p), "v"(v) : "memory");
}

__global__ void k_init(const float* __restrict__ Wih, const float* __restrict__ Whh,
                       const float* __restrict__ Wg,
                       unsigned short* __restrict__ Wihb, unsigned short* __restrict__ Whhb,
                       unsigned short* __restrict__ Wgb,
                       float* __restrict__ out_align, float* __restrict__ ctx_st,
                       float* __restrict__ h_st, unsigned* __restrict__ slots) {
  const size_t idx = (size_t)blockIdx.x * blockDim.x + threadIdx.x;
  const size_t stride = (size_t)gridDim.x * blockDim.x;
  f4 z4 = {0.f, 0.f, 0.f, 0.f};
  for (size_t i = idx; i < (size_t)BB * TT * SS / 4; i += stride) ((f4*)out_align)[i] = z4;
  for (size_t i = idx; i < (size_t)BB * HH / 4; i += stride) ((f4*)ctx_st)[i] = z4;
  for (size_t i = idx; i < (size_t)2 * BB * HH / 4; i += stride) ((f4*)h_st)[i] = z4;
  for (size_t i = idx; i < 1024; i += stride) slots[i] = 0u;
  for (size_t i = idx; i < (size_t)2048 * 1024; i += stride) Wihb[i] = f2bf(Wih[i]);
  for (size_t i = idx; i < (size_t)2048 * 512; i += stride) Whhb[i] = f2bf(Whh[i]);
  for (size_t i = idx; i < (size_t)48 * 512; i += stride) Wgb[i] = f2bf(Wg[i]);
}

// ---------------- 32 groups x 8 blocks x 1 batch: fan-in-8 barriers -------
// R7/R8 lesson: per-step time is ~15us of fixed serialized latency (two
// 32-wide LLC flag barriers dominate); work-halving only bought 2.2us and
// co-residency is either refused (2 blocks/CU) or spill-poisoned (1024thr).
// This kernel keeps the proven 256x512 resident shape and protocol, but
// cuts both all-to-all barriers from fan-in 32 to fan-in 8.
// Block owns 256 gate-cols = 64 h-dims x 4 gates of its group's 1 batch.
// Bonus: with linear dispatch (bid%8 = XCD), all 32 blocks per XCD share
// one 768KB weight slice -> L2-resident weights (perf-only assumption).
__global__ void __launch_bounds__(512, 2)
k_grp8(const float* __restrict__ input, const float* __restrict__ memory,
       const float* __restrict__ bih, const float* __restrict__ bhh,
       const float* __restrict__ bgv,
       const unsigned short* __restrict__ Wihb,
       const unsigned short* __restrict__ Whhb,
       const unsigned short* __restrict__ Wgb,
       float* __restrict__ out_ctx, float* __restrict__ out_align,
       float* __restrict__ ctx_st, float* __restrict__ h_st,
       unsigned* __restrict__ aslots, unsigned* __restrict__ bslots) {
  __shared__ float x_lds[PADR];
  __shared__ float c_lds[PADR];
  __shared__ float h_lds[PADR];
  __shared__ float gbuf[16 * 17];
  __shared__ float bias_s[256];
  __shared__ float c_s[64];
  __shared__ float w_s[SS];
  __shared__ float red2[8 * 68];
  __shared__ float phi_s[48];
  __shared__ float alpha_s[MM], rbeta_s[MM], ksi_s[MM], beta_s[MM];
  __shared__ int win_s[2];

  const int tid = threadIdx.x;
  const int bid = blockIdx.x;
  const int grp = bid >> 3;        // 32 groups of 8 blocks; group owns 1 batch
  const int rB  = bid & 7;         // rank in group -> 64 h-dims
  const int b   = grp;             // batch

  // phase-A thread coords: 32-way k split, 16 col-slots of 16 cols each
  const int ks = tid & 31;
  const int rq = tid >> 5;         // 0..15
  const int gt = rq >> 2;          // gate
  const int cq = rq & 3;           // col quad (16 cols each)
  const int colb = (rB << 6) + (cq << 4);
  const unsigned short* wiB = Wihb + (((size_t)(gt << 9) + colb) << 10) + (ks << 4);
  const unsigned short* whB = Whhb + (((size_t)(gt << 9) + colb) << 9) + (ks << 4);

  // phase-B coords: 8 blocks for the batch, 64-wide d-chunks
  const int pp = rB;

  // staging coords (128 threads stage the batch's 512 floats)
  const int sk = (tid & 127) << 2;
  const int ski = IDXH(sk);

  if (tid < 256) {
    const int row = ((tid >> 6) << 9) + (rB << 6) + (tid & 63);
    bias_s[tid] = bih[row] + bhh[row];
  }
  if (tid < 64) c_s[tid] = 0.f;
  if (tid < MM) ksi_s[tid] = 0.f;
  __syncthreads();

  float acc[16];

  // ---- prologue: stage x(0), h(-1)=0; compute x+h parts for t=0 ----
  if (tid < 128) {
    f4 xv = *(const f4*)(input + ((size_t)b * TT + 0) * HH + sk);
    f4 hv;
    ld1_sys(h_st + (size_t)b * HH + sk, hv);   // buffer 0 (zeroed)
    *(f4*)&x_lds[ski] = xv;
    *(f4*)&h_lds[ski] = hv;
  }
  __syncthreads();
#pragma unroll
  for (int j = 0; j < 16; ++j) acc[j] = 0.f;
#pragma unroll
  for (int i = 0; i < 4; ++i) {
    const int kx = 20 * ks + 4 * i;
    f4 xb = *(const f4*)&x_lds[kx];
    f4 hb = *(const f4*)&h_lds[kx];
#pragma unroll
    for (int j = 0; j < 16; ++j) {
      uint2 u = *(const uint2*)(wiB + (j << 10) + 4 * i);
      f4 wf;
      wf.x = __uint_as_float(u.x << 16); wf.y = __uint_as_float(u.x & 0xffff0000u);
      wf.z = __uint_as_float(u.y << 16); wf.w = __uint_as_float(u.y & 0xffff0000u);
      fma4(acc[j], xb, wf);
      uint2 v = *(const uint2*)(whB + (j << 9) + 4 * i);
      f4 wh;
      wh.x = __uint_as_float(v.x << 16); wh.y = __uint_as_float(v.x & 0xffff0000u);
      wh.z = __uint_as_float(v.y << 16); wh.w = __uint_as_float(v.y & 0xffff0000u);
      fma4(acc[j], hb, wh);
    }
  }

  for (int t = 0; t < TT; ++t) {
    const unsigned seq = (unsigned)(t + 1);
    const int nxt = (t + 1) & 1;     // buffer holding h(t)

    // ---- wait ctx(t-1) ready (fan-in 8), stage it ----
    if (tid < 8) {
      while (__hip_atomic_load(&bslots[(grp << 3) + tid], __ATOMIC_RELAXED,
                               __HIP_MEMORY_SCOPE_AGENT) < (unsigned)t) {}
    }
    __syncthreads();
    if (tid < 128) {
      f4 cv;
      ld1_sys(ctx_st + (size_t)b * HH + sk, cv);
      *(f4*)&c_lds[ski] = cv;
    }
    __syncthreads();

    // ---- ctx-part of gates(t) ----
#pragma unroll
    for (int i = 0; i < 4; ++i) {
      const int kx = 20 * ks + 4 * i;
      f4 cb = *(const f4*)&c_lds[kx];
#pragma unroll
      for (int j = 0; j < 16; ++j) {
        uint2 u = *(const uint2*)(wiB + 512 + (j << 10) + 4 * i);
        f4 wf;
        wf.x = __uint_as_float(u.x << 16); wf.y = __uint_as_float(u.x & 0xffff0000u);
        wf.z = __uint_as_float(u.y << 16); wf.w = __uint_as_float(u.y & 0xffff0000u);
        fma4(acc[j], cb, wf);
      }
    }
    // ---- reduce over ks (in-wave butterfly, ks = lane&31) ----
#pragma unroll
    for (int j = 0; j < 16; ++j) {
      float v = acc[j];
      v += __shfl_xor(v, 1, 64);
      v += __shfl_xor(v, 2, 64);
      v += __shfl_xor(v, 4, 64);
      v += __shfl_xor(v, 8, 64);
      v += __shfl_xor(v, 16, 64);
      acc[j] = v;
    }
    if ((tid & 31) == 0) {
#pragma unroll
      for (int j = 0; j < 16; ++j) gbuf[rq * 17 + j] = acc[j];
    }
    __syncthreads();
    // ---- LSTM cell (64 h-dims) + publish h(t) + flag A ----
    if (tid < 64) {
      const int cl = tid;
      const int cr = (cl >> 4) * 17 + (cl & 15);
      const float ig = gbuf[0 * 68 + cr] + bias_s[cl];
      const float fg = gbuf[4 * 17 + cr] + bias_s[64 + cl];
      const float gg = gbuf[8 * 17 + cr] + bias_s[128 + cl];
      const float og = gbuf[12 * 17 + cr] + bias_s[192 + cl];
      float c = sigm(fg) * c_s[tid] + sigm(ig) * tanhf(gg);
      c_s[tid] = c;
      const float h = sigm(og) * tanhf(c);
      st_sys(h_st + (((size_t)nxt * BB) + b) * HH + (rB << 6) + cl, h);
    }
    if (tid == 0)
      __hip_atomic_store(&aslots[(grp << 3) + rB], seq, __ATOMIC_RELEASE,
                         __HIP_MEMORY_SCOPE_AGENT);

    // ---- stage x(t+1) + compute x-part(t+1) (hides barrier-A hop) ----
    if (tid < 128) {
      const int tload = (t + 1 < TT) ? (t + 1) : t;
      f4 xv = *(const f4*)(input + ((size_t)b * TT + tload) * HH + sk);
      *(f4*)&x_lds[ski] = xv;
    }
    __syncthreads();
#pragma unroll
    for (int j = 0; j < 16; ++j) acc[j] = 0.f;
#pragma unroll
    for (int i = 0; i < 4; ++i) {
      const int kx = 20 * ks + 4 * i;
      f4 xb = *(const f4*)&x_lds[kx];
#pragma unroll
      for (int j = 0; j < 16; ++j) {
        uint2 u = *(const uint2*)(wiB + (j << 10) + 4 * i);
        f4 wf;
        wf.x = __uint_as_float(u.x << 16); wf.y = __uint_as_float(u.x & 0xffff0000u);
        wf.z = __uint_as_float(u.y << 16); wf.w = __uint_as_float(u.y & 0xffff0000u);
        fma4(acc[j], xb, wf);
      }
    }

    // ---- wait barrier A(t) (fan-in 8); stage h(t) ----
    if (tid < 8) {
      while (__hip_atomic_load(&aslots[(grp << 3) + tid], __ATOMIC_RELAXED,
                               __HIP_MEMORY_SCOPE_AGENT) < seq) {}
    }
    __syncthreads();
    if (tid < 128) {
      f4 hv;
      ld1_sys(h_st + (((size_t)nxt * BB) + b) * HH + sk, hv);
      *(f4*)&h_lds[ski] = hv;
    }
    __syncthreads();

    // ---- Phase B(t): 8 blocks for the batch ----
    {
      // phi = h @ Wg^T + bg (replicated across the batch's 8 blocks)
      const int wv2 = tid >> 6, lane2 = tid & 63;
#pragma unroll
      for (int e = 0; e < 6; ++e) {
        const int r2 = wv2 * 6 + e;
        const unsigned short* wr = Wgb + (r2 << 9);
        float pa = 0.f;
#pragma unroll
        for (int j2 = 0; j2 < 8; ++j2) {
          const int k = lane2 + (j2 << 6);
          pa = fmaf(bf2f(wr[k]), h_lds[IDXH(k)], pa);
        }
        pa += __shfl_xor(pa, 32, 64); pa += __shfl_xor(pa, 16, 64);
        pa += __shfl_xor(pa, 8, 64);  pa += __shfl_xor(pa, 4, 64);
        pa += __shfl_xor(pa, 2, 64);  pa += __shfl_xor(pa, 1, 64);
        if (lane2 == 0) phi_s[r2] = pa + bgv[r2];
      }
    }
    __syncthreads();
    if (tid < MM) {
      ksi_s[tid] += __expf(phi_s[tid]);
      beta_s[tid] = __expf(phi_s[MM + tid]);
    }
    __syncthreads();
    if (tid == 0) {
      float mx = -1e30f;
      for (int m = 0; m < MM; ++m) mx = fmaxf(mx, phi_s[2 * MM + m]);
      float ssum = 0.f; float ev[MM];
      for (int m = 0; m < MM; ++m) { ev[m] = __expf(phi_s[2 * MM + m] - mx); ssum += ev[m]; }
      const float inv = 1.f / ssum;
      float lo = 1e30f, hi = -1e30f;
      for (int m = 0; m < MM; ++m) {
        alpha_s[m] = ev[m] * inv;
        rbeta_s[m] = 1.f / beta_s[m];
        const float dd = 13.f * beta_s[m] + 3.f;
        lo = fminf(lo, ksi_s[m] - dd);
        hi = fmaxf(hi, ksi_s[m] + dd);
      }
      int ilo = (int)floorf(lo); if (ilo < 0) ilo = 0; if (ilo > SS) ilo = SS;
      int ihi = (int)ceilf(hi) + 1; if (ihi > SS) ihi = SS; if (ihi < ilo) ihi = ilo;
      win_s[0] = ilo; win_s[1] = ihi;
    }
    __syncthreads();
    const int ilo = win_s[0], ihi = win_s[1];
    {
      float* arow = out_align + ((size_t)b * TT + t) * SS;
      for (int s = ilo + tid; s < ihi; s += 512) {
        const float us = (float)s;
        float wsum = 0.f;
#pragma unroll
        for (int m = 0; m < MM; ++m) {
          const float rb2 = rbeta_s[m];
          const float z1 = (us + 1.5f - ksi_s[m]) * rb2;
          const float z0 = (us + 0.5f - ksi_s[m]) * rb2;
          wsum += alpha_s[m] * (sigm(z1) - sigm(z0));
        }
        w_s[s - ilo] = wsum;
        if (pp == 0) arow[s] = wsum;
      }
    }
    __syncthreads();
    {
      // ctx chunk: d in [64*pp, 64*pp+64), 8-way s-split
      const int dl = tid & 63, sg = tid >> 6;
      const int d = (pp << 6) + dl;
      float a3 = 0.f;
      int s = ilo + sg;
      const float* mp = memory + ((size_t)b * SS + s) * HH + d;
      for (; s + 24 < ihi; s += 32, mp += 32 * HH) {
        const float m0 = mp[0], m1 = mp[8 * HH], m2 = mp[16 * HH], m3 = mp[24 * HH];
        a3 = fmaf(w_s[s - ilo], m0, a3);
        a3 = fmaf(w_s[s + 8 - ilo], m1, a3);
        a3 = fmaf(w_s[s + 16 - ilo], m2, a3);
        a3 = fmaf(w_s[s + 24 - ilo], m3, a3);
      }
      for (; s < ihi; s += 8, mp += 8 * HH) a3 = fmaf(w_s[s - ilo], *mp, a3);
      red2[sg * 68 + dl] = a3;
    }
    __syncthreads();
    if (tid < 64) {
      float cv = 0.f;
#pragma unroll
      for (int g2 = 0; g2 < 8; ++g2) cv += red2[g2 * 68 + tid];
      st_sys(ctx_st + (size_t)b * HH + (pp << 6) + tid, cv);
      const size_t o = ((size_t)b * TT + t) * HH + (pp << 6) + tid;
      out_ctx[o] = cv + input[o];
    }
    if (tid == 0)
      __hip_atomic_store(&bslots[(grp << 3) + rB], seq, __ATOMIC_RELEASE,
                         __HIP_MEMORY_SCOPE_AGENT);

    // ---- h-part(t+1) (hides barrier-B hop + other blocks' B work) ----
    if (t + 1 < TT) {
#pragma unroll
      for (int i = 0; i < 4; ++i) {
        const int kx = 20 * ks + 4 * i;
        f4 hb = *(const f4*)&h_lds[kx];
#pragma unroll
        for (int j = 0; j < 16; ++j) {
          uint2 v = *(const uint2*)(whB + (j << 9) + 4 * i);
          f4 wh;
          wh.x = __uint_as_float(v.x << 16); wh.y = __uint_as_float(v.x & 0xffff0000u);
          wh.z = __uint_as_float(v.y << 16); wh.w = __uint_as_float(v.y & 0xffff0000u);
          fma4(acc[j], hb, wh);
        }
      }
    }
  }
}

// ---------------- proven 256x512 baseline (fallback) ----------------------
__global__ void __launch_bounds__(512, 2)
k_base(const float* __restrict__ input, const float* __restrict__ memory,
       const float* __restrict__ bih, const float* __restrict__ bhh,
       const float* __restrict__ bgv,
       const unsigned short* __restrict__ Wihb,
       const unsigned short* __restrict__ Whhb,
       const unsigned short* __restrict__ Wgb,
       float* __restrict__ out_ctx, float* __restrict__ out_align,
       float* __restrict__ ctx_st, float* __restrict__ h_st,
       unsigned* __restrict__ aslots, unsigned* __restrict__ bslots) {
  __shared__ float x_lds[4 * PADR];
  __shared__ float c_lds[4 * PADR];
  __shared__ float h_lds[4 * PADR];
  __shared__ float gbuf[16 * 17];
  __shared__ float bias_s[64];
  __shared__ float c_s[64];
  __shared__ float w_s[SS];
  __shared__ float red2[8 * 68];
  __shared__ float phi_s[48];
  __shared__ float alpha_s[MM], rbeta_s[MM], ksi_s[MM], beta_s[MM];
  __shared__ int win_s[2];

  const int tid = threadIdx.x;
  const int bid = blockIdx.x;
  const int grp = bid >> 5;
  const int rB  = bid & 31;
  const int B0  = grp << 2;

  const int ks = tid & 31;
  const int rq = tid >> 5;
  const int gt = rq >> 2;
  const int cq = rq & 3;
  const int colb = (rB << 4) + (cq << 2);
  const unsigned short* wiB = Wihb + (((size_t)(gt << 9) + colb) << 10) + (ks << 4);
  const unsigned short* whB = Whhb + (((size_t)(gt << 9) + colb) << 9) + (ks << 4);

  const int bq = rB >> 3;
  const int pp = rB & 7;
  const int b  = B0 + bq;

  const int sb = tid >> 7;
  const int sk = (tid & 127) << 2;
  const int ski = IDXH(sk);

  if (tid < 64) {
    const int row = ((tid >> 4) << 9) + (rB << 4) + (tid & 15);
    bias_s[tid] = bih[row] + bhh[row];
    c_s[tid] = 0.f;
  }
  if (tid < MM) ksi_s[tid] = 0.f;
  __syncthreads();

  float acc[4][4];

  {
    f4 xv = *(const f4*)(input + ((size_t)(B0 + sb) * TT + 0) * HH + sk);
    f4 hv;
    ld1_sys(h_st + (size_t)(B0 + sb) * HH + sk, hv);
    *(f4*)&x_lds[sb * PADR + ski] = xv;
    *(f4*)&h_lds[sb * PADR + ski] = hv;
  }
  __syncthreads();
#pragma unroll
  for (int j = 0; j < 4; ++j)
#pragma unroll
    for (int b2 = 0; b2 < 4; ++b2) acc[j][b2] = 0.f;
#pragma unroll
  for (int i = 0; i < 4; ++i) {
    const int kx = 20 * ks + 4 * i;
    f4 xb0 = *(const f4*)&x_lds[0 * PADR + kx];
    f4 xb1 = *(const f4*)&x_lds[1 * PADR + kx];
    f4 xb2 = *(const f4*)&x_lds[2 * PADR + kx];
    f4 xb3 = *(const f4*)&x_lds[3 * PADR + kx];
    f4 hb0 = *(const f4*)&h_lds[0 * PADR + kx];
    f4 hb1 = *(const f4*)&h_lds[1 * PADR + kx];
    f4 hb2 = *(const f4*)&h_lds[2 * PADR + kx];
    f4 hb3 = *(const f4*)&h_lds[3 * PADR + kx];
#pragma unroll
    for (int j = 0; j < 4; ++j) {
      uint2 u = *(const uint2*)(wiB + (j << 10) + 4 * i);
      f4 wf;
      wf.x = __uint_as_float(u.x << 16); wf.y = __uint_as_float(u.x & 0xffff0000u);
      wf.z = __uint_as_float(u.y << 16); wf.w = __uint_as_float(u.y & 0xffff0000u);
      fma4(acc[j][0], xb0, wf); fma4(acc[j][1], xb1, wf);
      fma4(acc[j][2], xb2, wf); fma4(acc[j][3], xb3, wf);
      uint2 v = *(const uint2*)(whB + (j << 9) + 4 * i);
      f4 wh;
      wh.x = __uint_as_float(v.x << 16); wh.y = __uint_as_float(v.x & 0xffff0000u);
      wh.z = __uint_as_float(v.y << 16); wh.w = __uint_as_float(v.y & 0xffff0000u);
      fma4(acc[j][0], hb0, wh); fma4(acc[j][1], hb1, wh);
      fma4(acc[j][2], hb2, wh); fma4(acc[j][3], hb3, wh);
    }
  }

  for (int t = 0; t < TT; ++t) {
    const unsigned seq = (unsigned)(t + 1);
    const int nxt = (t + 1) & 1;

    if (tid < 32) {
      while (__hip_atomic_load(&bslots[(grp << 5) + tid], __ATOMIC_RELAXED,
                               __HIP_MEMORY_SCOPE_AGENT) < (unsigned)t) {}
    }
    __syncthreads();
    {
      f4 cv;
      ld1_sys(ctx_st + (size_t)(B0 + sb) * HH + sk, cv);
      *(f4*)&c_lds[sb * PADR + ski] = cv;
    }
    __syncthreads();

#pragma unroll
    for (int i = 0; i < 4; ++i) {
      const int kx = 20 * ks + 4 * i;
      f4 cb0 = *(const f4*)&c_lds[0 * PADR + kx];
      f4 cb1 = *(const f4*)&c_lds[1 * PADR + kx];
      f4 cb2 = *(const f4*)&c_lds[2 * PADR + kx];
      f4 cb3 = *(const f4*)&c_lds[3 * PADR + kx];
#pragma unroll
      for (int j = 0; j < 4; ++j) {
        uint2 u = *(const uint2*)(wiB + 512 + (j << 10) + 4 * i);
        f4 wf;
        wf.x = __uint_as_float(u.x << 16); wf.y = __uint_as_float(u.x & 0xffff0000u);
        wf.z = __uint_as_float(u.y << 16); wf.w = __uint_as_float(u.y & 0xffff0000u);
        fma4(acc[j][0], cb0, wf); fma4(acc[j][1], cb1, wf);
        fma4(acc[j][2], cb2, wf); fma4(acc[j][3], cb3, wf);
      }
    }
#pragma unroll
    for (int j = 0; j < 4; ++j)
#pragma unroll
      for (int b2 = 0; b2 < 4; ++b2) {
        float v = acc[j][b2];
        v += __shfl_xor(v, 1, 64);
        v += __shfl_xor(v, 2, 64);
        v += __shfl_xor(v, 4, 64);
        v += __shfl_xor(v, 8, 64);
        v += __shfl_xor(v, 16, 64);
        acc[j][b2] = v;
      }
    if ((tid & 31) == 0) {
#pragma unroll
      for (int j = 0; j < 4; ++j)
#pragma unroll
        for (int b2 = 0; b2 < 4; ++b2)
          gbuf[((b2 << 2) + gt) * 17 + (cq << 2) + j] = acc[j][b2];
    }
    __syncthreads();
    if (tid < 64) {
      const int b2 = tid >> 4, cl = tid & 15;
      const float ig = gbuf[((b2 << 2) + 0) * 17 + cl] + bias_s[cl];
      const float fg = gbuf[((b2 << 2) + 1) * 17 + cl] + bias_s[16 + cl];
      const float gg = gbuf[((b2 << 2) + 2) * 17 + cl] + bias_s[32 + cl];
      const float og = gbuf[((b2 << 2) + 3) * 17 + cl] + bias_s[48 + cl];
      float c = sigm(fg) * c_s[tid] + sigm(ig) * tanhf(gg);
      c_s[tid] = c;
      const float h = sigm(og) * tanhf(c);
      st_sys(h_st + (((size_t)nxt * BB) + B0 + b2) * HH + (rB << 4) + cl, h);
    }
    if (tid == 0)
      __hip_atomic_store(&aslots[(grp << 5) + rB], seq, __ATOMIC_RELEASE,
                         __HIP_MEMORY_SCOPE_AGENT);

    {
      const int tload = (t + 1 < TT) ? (t + 1) : t;
      f4 xv = *(const f4*)(input + ((size_t)(B0 + sb) * TT + tload) * HH + sk);
      *(f4*)&x_lds[sb * PADR + ski] = xv;
    }
    __syncthreads();
#pragma unroll
    for (int j = 0; j < 4; ++j)
#pragma unroll
      for (int b2 = 0; b2 < 4; ++b2) acc[j][b2] = 0.f;
#pragma unroll
    for (int i = 0; i < 4; ++i) {
      const int kx = 20 * ks + 4 * i;
      f4 xb0 = *(const f4*)&x_lds[0 * PADR + kx];
      f4 xb1 = *(const f4*)&x_lds[1 * PADR + kx];
      f4 xb2 = *(const f4*)&x_lds[2 * PADR + kx];
      f4 xb3 = *(const f4*)&x_lds[3 * PADR + kx];
#pragma unroll
      for (int j = 0; j < 4; ++j) {
        uint2 u = *(const uint2*)(wiB + (j << 10) + 4 * i);
        f4 wf;
        wf.x = __uint_as_float(u.x << 16); wf.y = __uint_as_float(u.x & 0xffff0000u);
        wf.z = __uint_as_float(u.y << 16); wf.w = __uint_as_float(u.y & 0xffff0000u);
        fma4(acc[j][0], xb0, wf); fma4(acc[j][1], xb1, wf);
        fma4(acc[j][2], xb2, wf); fma4(acc[j][3], xb3, wf);
      }
    }

    if (tid < 32) {
      while (__hip_atomic_load(&aslots[(grp << 5) + tid], __ATOMIC_RELAXED,
                               __HIP_MEMORY_SCOPE_AGENT) < seq) {}
    }
    __syncthreads();
    {
      f4 hv;
      ld1_sys(h_st + (((size_t)nxt * BB) + B0 + sb) * HH + sk, hv);
      *(f4*)&h_lds[sb * PADR + ski] = hv;
    }
    __syncthreads();

    {
      const int wv2 = tid >> 6, lane2 = tid & 63;
#pragma unroll
      for (int e = 0; e < 6; ++e) {
        const int r2 = wv2 * 6 + e;
        const unsigned short* wr = Wgb + (r2 << 9);
        float pa = 0.f;
#pragma unroll
        for (int j2 = 0; j2 < 8; ++j2) {
          const int k = lane2 + (j2 << 6);
          pa = fmaf(bf2f(wr[k]), h_lds[bq * PADR + IDXH(k)], pa);
        }
        pa += __shfl_xor(pa, 32, 64); pa += __shfl_xor(pa, 16, 64);
        pa += __shfl_xor(pa, 8, 64);  pa += __shfl_xor(pa, 4, 64);
        pa += __shfl_xor(pa, 2, 64);  pa += __shfl_xor(pa, 1, 64);
        if (lane2 == 0) phi_s[r2] = pa + bgv[r2];
      }
    }
    __syncthreads();
    if (tid < MM) {
      ksi_s[tid] += __expf(phi_s[tid]);
      beta_s[tid] = __expf(phi_s[MM + tid]);
    }
    __syncthreads();
    if (tid == 0) {
      float mx = -1e30f;
      for (int m = 0; m < MM; ++m) mx = fmaxf(mx, phi_s[2 * MM + m]);
      float ssum = 0.f; float ev[MM];
      for (int m = 0; m < MM; ++m) { ev[m] = __expf(phi_s[2 * MM + m] - mx); ssum += ev[m]; }
      const float inv = 1.f / ssum;
      float lo = 1e30f, hi = -1e30f;
      for (int m = 0; m < MM; ++m) {
        alpha_s[m] = ev[m] * inv;
        rbeta_s[m] = 1.f / beta_s[m];
        const float dd = 13.f * beta_s[m] + 3.f;
        lo = fminf(lo, ksi_s[m] - dd);
        hi = fmaxf(hi, ksi_s[m] + dd);
      }
      int ilo = (int)floorf(lo); if (ilo < 0) ilo = 0; if (ilo > SS) ilo = SS;
      int ihi = (int)ceilf(hi) + 1; if (ihi > SS) ihi = SS; if (ihi < ilo) ihi = ilo;
      win_s[0] = ilo; win_s[1] = ihi;
    }
    __syncthreads();
    const int ilo = win_s[0], ihi = win_s[1];
    {
      float* arow = out_align + ((size_t)b * TT + t) * SS;
      for (int s = ilo + tid; s < ihi; s += 512) {
        const float us = (float)s;
        float wsum = 0.f;
#pragma unroll
        for (int m = 0; m < MM; ++m) {
          const float rb2 = rbeta_s[m];
          const float z1 = (us + 1.5f - ksi_s[m]) * rb2;
          const float z0 = (us + 0.5f - ksi_s[m]) * rb2;
          wsum += alpha_s[m] * (sigm(z1) - sigm(z0));
        }
        w_s[s - ilo] = wsum;
        if (pp == 0) arow[s] = wsum;
      }
    }
    __syncthreads();
    {
      const int dl = tid & 63, sg = tid >> 6;
      const int d = (pp << 6) + dl;
      float a3 = 0.f;
      int s = ilo + sg;
      const float* mp = memory + ((size_t)b * SS + s) * HH + d;
      for (; s + 24 < ihi; s += 32, mp += 32 * HH) {
        const float m0 = mp[0], m1 = mp[8 * HH], m2 = mp[16 * HH], m3 = mp[24 * HH];
        a3 = fmaf(w_s[s - ilo], m0, a3);
        a3 = fmaf(w_s[s + 8 - ilo], m1, a3);
        a3 = fmaf(w_s[s + 16 - ilo], m2, a3);
        a3 = fmaf(w_s[s + 24 - ilo], m3, a3);
      }
      for (; s < ihi; s += 8, mp += 8 * HH) a3 = fmaf(w_s[s - ilo], *mp, a3);
      red2[sg * 68 + dl] = a3;
    }
    __syncthreads();
    if (tid < 64) {
      float cv = 0.f;
#pragma unroll
      for (int g2 = 0; g2 < 8; ++g2) cv += red2[g2 * 68 + tid];
      st_sys(ctx_st + (size_t)b * HH + (pp << 6) + tid, cv);
      const size_t o = ((size_t)b * TT + t) * HH + (pp << 6) + tid;
      out_ctx[o] = cv + input[o];
    }
    if (tid == 0)
      __hip_atomic_store(&bslots[(grp << 5) + rB], seq, __ATOMIC_RELEASE,
                         __HIP_MEMORY_SCOPE_AGENT);

    if (t + 1 < TT) {
#pragma unroll
      for (int i = 0; i < 4; ++i) {
        const int kx = 20 * ks + 4 * i;
        f4 hb0 = *(const f4*)&h_lds[0 * PADR + kx];
        f4 hb1 = *(const f4*)&h_lds[1 * PADR + kx];
        f4 hb2 = *(const f4*)&h_lds[2 * PADR + kx];
        f4 hb3 = *(const f4*)&h_lds[3 * PADR + kx];
#pragma unroll
        for (int j = 0; j < 4; ++j) {
          uint2 v = *(const uint2*)(whB + (j << 9) + 4 * i);
          f4 wh;
          wh.x = __uint_as_float(v.x << 16); wh.y = __uint_as_float(v.x & 0xffff0000u);
          wh.z = __uint_as_float(v.y << 16); wh.w = __uint_as_float(v.y & 0xffff0000u);
          fma4(acc[j][0], hb0, wh); fma4(acc[j][1], hb1, wh);
          fma4(acc[j][2], hb2, wh); fma4(acc[j][3], hb3, wh);
        }
      }
    }
  }
}

extern "C" void kernel_launch(void* const* d_in, const int* in_sizes, int n_in,
                              void* d_out, int out_size, void* d_ws, size_t ws_size,
                              hipStream_t stream) {
  const float* input = (const float*)d_in[0];
  const float* memory = (const float*)d_in[1];
  const float* Wih = (const float*)d_in[2];
  const float* Whh = (const float*)d_in[3];
  const float* bih = (const float*)d_in[4];
  const float* bhh = (const float*)d_in[5];
  const float* Wg = (const float*)d_in[6];
  const float* bgv = (const float*)d_in[7];
  float* out_ctx = (float*)d_out;
  float* out_align = out_ctx + (size_t)BB * TT * HH;

  char* ws = (char*)d_ws;
  unsigned* slots = (unsigned*)(ws + WS_SLOTS);
  unsigned* aslots = slots;
  unsigned* bslots = slots + 512;
  float* ctx_st = (float*)(ws + WS_CTX);
  float* h_st = (float*)(ws + WS_H);
  unsigned short* Wihb = (unsigned short*)(ws + WS_WIHB);
  unsigned short* Whhb = (unsigned short*)(ws + WS_WHHB);
  unsigned short* Wgb = (unsigned short*)(ws + WS_WGB);

  k_init<<<dim3(2048), dim3(256), 0, stream>>>(Wih, Whh, Wg, Wihb, Whhb, Wgb,
                                               out_align, ctx_st, h_st, slots);

  void* args[] = { (void*)&input, (void*)&memory, (void*)&bih, (void*)&bhh, (void*)&bgv,
                   (void*)&Wihb, (void*)&Whhb, (void*)&Wgb,
                   (void*)&out_ctx, (void*)&out_align,
                   (void*)&ctx_st, (void*)&h_st, (void*)&aslots, (void*)&bslots };

  // 32 groups x 8 blocks (fan-in-8 barriers), proven-resident 256x512 shape.
  // Fall back to the proven baseline on launch error.
  hipError_t le = hipLaunchCooperativeKernel((void*)k_grp8, dim3(256),
                                             dim3(512), args, 0, stream);
  if (le != hipSuccess) {
    hipLaunchCooperativeKernel((void*)k_base, dim3(256), dim3(512),
                               args, 0, stream);
  }
}

// Round 10
// 8627.805 us; speedup vs baseline: 2.8579x; 2.8579x over previous
//
#include <hip/hip_runtime.h>

#define BB 32
#define TT 512
#define SS 1024
#define HH 512
#define MM 16

typedef float f4 __attribute__((ext_vector_type(4)));

// d_ws layout (bytes)
#define WS_SLOTS  0          // 1024 u32 (512 aslots + 512 bslots)
#define WS_CTX    4096       // 32*512 f32
#define WS_H      69632      // 2*32*512 f32
#define WS_WIHB   200704     // 2048*1024 bf16 (4 MB)
#define WS_WHHB   4395008    // 2048*512 bf16 (2 MB)
#define WS_WGB    6492160    // 48*512 bf16 (48 KB)
#define WS_PHIA   6541312    // 2*32*48 f32 (12 KB) phi partial accumulator

#define PADR 640
#define IDXH(k) ((k) + (((k) >> 4) << 2))

__device__ __forceinline__ float sigm(float z) { return 1.f / (1.f + __expf(-z)); }
__device__ __forceinline__ float bf2f(unsigned short u) {
  return __uint_as_float((unsigned)u << 16);
}
__device__ __forceinline__ unsigned short f2bf(float f) {
  unsigned u = __float_as_uint(f);
  return (unsigned short)((u + 0x7fffu + ((u >> 16) & 1u)) >> 16);
}
__device__ __forceinline__ void fma4(float& a, const f4& u, const f4& v) {
  a = fmaf(u.x, v.x, fmaf(u.y, v.y, fmaf(u.z, v.z, fmaf(u.w, v.w, a))));
}

// LLC-coherent ops (bypass L1/L2)
__device__ __forceinline__ void ld1_sys(const float* p0, f4& a) {
  asm volatile("global_load_dwordx4 %0, %1, off sc1\n\ts_waitcnt vmcnt(0)"
               : "=&v"(a) : "v"(p0) : "memory");
}
__device__ __forceinline__ void ld1f_sys(const float* p0, float& a) {
  asm volatile("global_load_dword %0, %1, off sc1\n\ts_waitcnt vmcnt(0)"
               : "=&v"(a) : "v"(p0) : "memory");
}
__device__ __forceinline__ void st_sys(float* p, float v) {
  asm volatile("global_store_dword %0, %1, off sc1" :: "v"(p), "v"(v) : "memory");
}

__global__ void k_init(const float* __restrict__ Wih, const float* __restrict__ Whh,
                       const float* __restrict__ Wg,
                       unsigned short* __restrict__ Wihb, unsigned short* __restrict__ Whhb,
                       unsigned short* __restrict__ Wgb,
                       float* __restrict__ out_align, float* __restrict__ ctx_st,
                       float* __restrict__ h_st, unsigned* __restrict__ slots,
                       float* __restrict__ phi_acc) {
  const size_t idx = (size_t)blockIdx.x * blockDim.x + threadIdx.x;
  const size_t stride = (size_t)gridDim.x * blockDim.x;
  f4 z4 = {0.f, 0.f, 0.f, 0.f};
  for (size_t i = idx; i < (size_t)BB * TT * SS / 4; i += stride) ((f4*)out_align)[i] = z4;
  for (size_t i = idx; i < (size_t)BB * HH / 4; i += stride) ((f4*)ctx_st)[i] = z4;
  for (size_t i = idx; i < (size_t)2 * BB * HH / 4; i += stride) ((f4*)h_st)[i] = z4;
  for (size_t i = idx; i < 1024; i += stride) slots[i] = 0u;
  for (size_t i = idx; i < (size_t)2 * BB * 48; i += stride) phi_acc[i] = 0.f;
  for (size_t i = idx; i < (size_t)2048 * 1024; i += stride) Wihb[i] = f2bf(Wih[i]);
  for (size_t i = idx; i < (size_t)2048 * 512; i += stride) Whhb[i] = f2bf(Whh[i]);
  for (size_t i = idx; i < (size_t)48 * 512; i += stride) Wgb[i] = f2bf(Wg[i]);
}

// Proven 8-group x 32-block baseline, with ONE change (R9 theory): the LSTM
// wave computes phi partials from its own h-slice and atomicAdds them into
// phi_acc BEFORE flagging A; phase B loads the 48 summed floats instead of
// staging h + running the 48x512 phi GEMM. h staging + Whh-GEMM move after
// the B-flag (hidden in the next ctx-wait). Weight partitioning untouched
// (R9: 768KB slices broke L2 locality -> fetch-bound disaster).
__global__ void __launch_bounds__(512, 2)
k_main(const float* __restrict__ input, const float* __restrict__ memory,
       const float* __restrict__ bih, const float* __restrict__ bhh,
       const float* __restrict__ bgv,
       const unsigned short* __restrict__ Wihb,
       const unsigned short* __restrict__ Whhb,
       const unsigned short* __restrict__ Wgb,
       float* __restrict__ out_ctx, float* __restrict__ out_align,
       float* __restrict__ ctx_st, float* __restrict__ h_st,
       unsigned* __restrict__ aslots, unsigned* __restrict__ bslots,
       float* __restrict__ phi_acc) {
  __shared__ float x_lds[4 * PADR];
  __shared__ float c_lds[4 * PADR];
  __shared__ float h_lds[4 * PADR];
  __shared__ float gbuf[16 * 17];
  __shared__ float bias_s[64];
  __shared__ float c_s[64];
  __shared__ float h_sl[64];
  __shared__ float w_s[SS];
  __shared__ float red2[8 * 68];
  __shared__ float phi_s[48];
  __shared__ float alpha_s[MM], rbeta_s[MM], ksi_s[MM], beta_s[MM];
  __shared__ int win_s[2];

  const int tid = threadIdx.x;
  const int bid = blockIdx.x;
  const int grp = bid >> 5;        // 8 groups of 32 blocks; group owns 4 batches
  const int rB  = bid & 31;        // rank in group -> 16 gate-cols
  const int B0  = grp << 2;

  // phase-A thread coords
  const int ks = tid & 31;
  const int rq = tid >> 5;
  const int gt = rq >> 2;
  const int cq = rq & 3;
  const int colb = (rB << 4) + (cq << 2);
  const unsigned short* wiB = Wihb + (((size_t)(gt << 9) + colb) << 10) + (ks << 4);
  const unsigned short* whB = Whhb + (((size_t)(gt << 9) + colb) << 9) + (ks << 4);

  // phase-B coords: 8 blocks per batch
  const int bq = rB >> 3;
  const int pp = rB & 7;
  const int b  = B0 + bq;

  // staging coords
  const int sb = tid >> 7;
  const int sk = (tid & 127) << 2;
  const int ski = IDXH(sk);

  if (tid < 64) {
    const int row = ((tid >> 4) << 9) + (rB << 4) + (tid & 15);
    bias_s[tid] = bih[row] + bhh[row];
    c_s[tid] = 0.f;
  }
  if (tid < MM) ksi_s[tid] = 0.f;
  __syncthreads();

  float acc[4][4];

  // ---- prologue: stage x(0), h(-1)=0; compute x+h parts for t=0 ----
  {
    f4 xv = *(const f4*)(input + ((size_t)(B0 + sb) * TT + 0) * HH + sk);
    f4 hv;
    ld1_sys(h_st + (size_t)(B0 + sb) * HH + sk, hv);
    *(f4*)&x_lds[sb * PADR + ski] = xv;
    *(f4*)&h_lds[sb * PADR + ski] = hv;
  }
  __syncthreads();
#pragma unroll
  for (int j = 0; j < 4; ++j)
#pragma unroll
    for (int b2 = 0; b2 < 4; ++b2) acc[j][b2] = 0.f;
#pragma unroll
  for (int i = 0; i < 4; ++i) {
    const int kx = 20 * ks + 4 * i;
    f4 xb0 = *(const f4*)&x_lds[0 * PADR + kx];
    f4 xb1 = *(const f4*)&x_lds[1 * PADR + kx];
    f4 xb2 = *(const f4*)&x_lds[2 * PADR + kx];
    f4 xb3 = *(const f4*)&x_lds[3 * PADR + kx];
    f4 hb0 = *(const f4*)&h_lds[0 * PADR + kx];
    f4 hb1 = *(const f4*)&h_lds[1 * PADR + kx];
    f4 hb2 = *(const f4*)&h_lds[2 * PADR + kx];
    f4 hb3 = *(const f4*)&h_lds[3 * PADR + kx];
#pragma unroll
    for (int j = 0; j < 4; ++j) {
      uint2 u = *(const uint2*)(wiB + (j << 10) + 4 * i);
      f4 wf;
      wf.x = __uint_as_float(u.x << 16); wf.y = __uint_as_float(u.x & 0xffff0000u);
      wf.z = __uint_as_float(u.y << 16); wf.w = __uint_as_float(u.y & 0xffff0000u);
      fma4(acc[j][0], xb0, wf); fma4(acc[j][1], xb1, wf);
      fma4(acc[j][2], xb2, wf); fma4(acc[j][3], xb3, wf);
      uint2 v = *(const uint2*)(whB + (j << 9) + 4 * i);
      f4 wh;
      wh.x = __uint_as_float(v.x << 16); wh.y = __uint_as_float(v.x & 0xffff0000u);
      wh.z = __uint_as_float(v.y << 16); wh.w = __uint_as_float(v.y & 0xffff0000u);
      fma4(acc[j][0], hb0, wh); fma4(acc[j][1], hb1, wh);
      fma4(acc[j][2], hb2, wh); fma4(acc[j][3], hb3, wh);
    }
  }

  for (int t = 0; t < TT; ++t) {
    const unsigned seq = (unsigned)(t + 1);
    const int nxt = (t + 1) & 1;

    // ---- wait ctx(t-1) ready, stage it; rB==0 zeroes phi buffer (t+1)&1 ----
    if (tid < 32) {
      while (__hip_atomic_load(&bslots[(grp << 5) + tid], __ATOMIC_RELAXED,
                               __HIP_MEMORY_SCOPE_AGENT) < (unsigned)t) {}
    }
    __syncthreads();
    {
      f4 cv;
      ld1_sys(ctx_st + (size_t)(B0 + sb) * HH + sk, cv);
      *(f4*)&c_lds[sb * PADR + ski] = cv;
    }
    if (rB == 0 && tid >= 320 && tid < 512) {
      const int e = tid - 320;   // 0..191 = 4 batches x 48
      st_sys(phi_acc + ((size_t)nxt * BB + B0 + (e / 48)) * 48 + (e % 48), 0.f);
    }
    __syncthreads();

    // ---- ctx-part of gates(t) ----
#pragma unroll
    for (int i = 0; i < 4; ++i) {
      const int kx = 20 * ks + 4 * i;
      f4 cb0 = *(const f4*)&c_lds[0 * PADR + kx];
      f4 cb1 = *(const f4*)&c_lds[1 * PADR + kx];
      f4 cb2 = *(const f4*)&c_lds[2 * PADR + kx];
      f4 cb3 = *(const f4*)&c_lds[3 * PADR + kx];
#pragma unroll
      for (int j = 0; j < 4; ++j) {
        uint2 u = *(const uint2*)(wiB + 512 + (j << 10) + 4 * i);
        f4 wf;
        wf.x = __uint_as_float(u.x << 16); wf.y = __uint_as_float(u.x & 0xffff0000u);
        wf.z = __uint_as_float(u.y << 16); wf.w = __uint_as_float(u.y & 0xffff0000u);
        fma4(acc[j][0], cb0, wf); fma4(acc[j][1], cb1, wf);
        fma4(acc[j][2], cb2, wf); fma4(acc[j][3], cb3, wf);
      }
    }
    // ---- reduce over ks ----
#pragma unroll
    for (int j = 0; j < 4; ++j)
#pragma unroll
      for (int b2 = 0; b2 < 4; ++b2) {
        float v = acc[j][b2];
        v += __shfl_xor(v, 1, 64);
        v += __shfl_xor(v, 2, 64);
        v += __shfl_xor(v, 4, 64);
        v += __shfl_xor(v, 8, 64);
        v += __shfl_xor(v, 16, 64);
        acc[j][b2] = v;
      }
    if ((tid & 31) == 0) {
#pragma unroll
      for (int j = 0; j < 4; ++j)
#pragma unroll
        for (int b2 = 0; b2 < 4; ++b2)
          gbuf[((b2 << 2) + gt) * 17 + (cq << 2) + j] = acc[j][b2];
    }
    __syncthreads();
    // ---- LSTM cell + publish h(t) + phi partials + flag A (one wave) ----
    if (tid < 64) {
      const int b2 = tid >> 4, cl = tid & 15;
      const float ig = gbuf[((b2 << 2) + 0) * 17 + cl] + bias_s[cl];
      const float fg = gbuf[((b2 << 2) + 1) * 17 + cl] + bias_s[16 + cl];
      const float gg = gbuf[((b2 << 2) + 2) * 17 + cl] + bias_s[32 + cl];
      const float og = gbuf[((b2 << 2) + 3) * 17 + cl] + bias_s[48 + cl];
      float c = sigm(fg) * c_s[tid] + sigm(ig) * tanhf(gg);
      c_s[tid] = c;
      const float h = sigm(og) * tanhf(c);
      h_sl[tid] = h;
      st_sys(h_st + (((size_t)nxt * BB) + B0 + b2) * HH + (rB << 4) + cl, h);
      // phi partials: 3 (batch,row) pairs per lane (192 = 4 batches x 48 rows)
#pragma unroll
      for (int q = 0; q < 3; ++q) {
        const int e = q * 64 + tid;
        const int bp = e / 48, r2 = e % 48;
        const unsigned short* wr = Wgb + (r2 << 9) + (rB << 4);
        float pa = 0.f;
#pragma unroll
        for (int c2 = 0; c2 < 4; ++c2) {
          uint2 u = *(const uint2*)(wr + (c2 << 2));
          const float* hb = &h_sl[(bp << 4) + (c2 << 2)];
          pa = fmaf(__uint_as_float(u.x << 16), hb[0], pa);
          pa = fmaf(__uint_as_float(u.x & 0xffff0000u), hb[1], pa);
          pa = fmaf(__uint_as_float(u.y << 16), hb[2], pa);
          pa = fmaf(__uint_as_float(u.y & 0xffff0000u), hb[3], pa);
        }
        __hip_atomic_fetch_add(phi_acc + ((size_t)nxt * BB + B0 + bp) * 48 + r2,
                               pa, __ATOMIC_RELAXED, __HIP_MEMORY_SCOPE_AGENT);
      }
    }
    if (tid == 0)
      __hip_atomic_store(&aslots[(grp << 5) + rB], seq, __ATOMIC_RELEASE,
                         __HIP_MEMORY_SCOPE_AGENT);

    // ---- stage x(t+1) + compute x-part(t+1) (hides barrier-A hop) ----
    {
      const int tload = (t + 1 < TT) ? (t + 1) : t;
      f4 xv = *(const f4*)(input + ((size_t)(B0 + sb) * TT + tload) * HH + sk);
      *(f4*)&x_lds[sb * PADR + ski] = xv;
    }
    __syncthreads();
#pragma unroll
    for (int j = 0; j < 4; ++j)
#pragma unroll
      for (int b2 = 0; b2 < 4; ++b2) acc[j][b2] = 0.f;
#pragma unroll
    for (int i = 0; i < 4; ++i) {
      const int kx = 20 * ks + 4 * i;
      f4 xb0 = *(const f4*)&x_lds[0 * PADR + kx];
      f4 xb1 = *(const f4*)&x_lds[1 * PADR + kx];
      f4 xb2 = *(const f4*)&x_lds[2 * PADR + kx];
      f4 xb3 = *(const f4*)&x_lds[3 * PADR + kx];
#pragma unroll
      for (int j = 0; j < 4; ++j) {
        uint2 u = *(const uint2*)(wiB + (j << 10) + 4 * i);
        f4 wf;
        wf.x = __uint_as_float(u.x << 16); wf.y = __uint_as_float(u.x & 0xffff0000u);
        wf.z = __uint_as_float(u.y << 16); wf.w = __uint_as_float(u.y & 0xffff0000u);
        fma4(acc[j][0], xb0, wf); fma4(acc[j][1], xb1, wf);
        fma4(acc[j][2], xb2, wf); fma4(acc[j][3], xb3, wf);
      }
    }

    // ---- wait barrier A(t); read summed phi (no h stage, no phi GEMM) ----
    if (tid < 32) {
      while (__hip_atomic_load(&aslots[(grp << 5) + tid], __ATOMIC_RELAXED,
                               __HIP_MEMORY_SCOPE_AGENT) < seq) {}
    }
    __syncthreads();
    if (tid < 48) {
      float pv;
      ld1f_sys(phi_acc + ((size_t)nxt * BB + b) * 48 + tid, pv);
      phi_s[tid] = pv + bgv[tid];
    }
    __syncthreads();
    if (tid < MM) {
      ksi_s[tid] += __expf(phi_s[tid]);
      beta_s[tid] = __expf(phi_s[MM + tid]);
    }
    __syncthreads();
    if (tid == 0) {
      float mx = -1e30f;
      for (int m = 0; m < MM; ++m) mx = fmaxf(mx, phi_s[2 * MM + m]);
      float ssum = 0.f; float ev[MM];
      for (int m = 0; m < MM; ++m) { ev[m] = __expf(phi_s[2 * MM + m] - mx); ssum += ev[m]; }
      const float inv = 1.f / ssum;
      float lo = 1e30f, hi = -1e30f;
      for (int m = 0; m < MM; ++m) {
        alpha_s[m] = ev[m] * inv;
        rbeta_s[m] = 1.f / beta_s[m];
        const float dd = 13.f * beta_s[m] + 3.f;
        lo = fminf(lo, ksi_s[m] - dd);
        hi = fmaxf(hi, ksi_s[m] + dd);
      }
      int ilo = (int)floorf(lo); if (ilo < 0) ilo = 0; if (ilo > SS) ilo = SS;
      int ihi = (int)ceilf(hi) + 1; if (ihi > SS) ihi = SS; if (ihi < ilo) ihi = ilo;
      win_s[0] = ilo; win_s[1] = ihi;
    }
    __syncthreads();
    const int ilo = win_s[0], ihi = win_s[1];
    {
      float* arow = out_align + ((size_t)b * TT + t) * SS;
      for (int s = ilo + tid; s < ihi; s += 512) {
        const float us = (float)s;
        float wsum = 0.f;
#pragma unroll
        for (int m = 0; m < MM; ++m) {
          const float rb2 = rbeta_s[m];
          const float z1 = (us + 1.5f - ksi_s[m]) * rb2;
          const float z0 = (us + 0.5f - ksi_s[m]) * rb2;
          wsum += alpha_s[m] * (sigm(z1) - sigm(z0));
        }
        w_s[s - ilo] = wsum;
        if (pp == 0) arow[s] = wsum;
      }
    }
    __syncthreads();
    {
      const int dl = tid & 63, sg = tid >> 6;
      const int d = (pp << 6) + dl;
      float a3 = 0.f;
      int s = ilo + sg;
      const float* mp = memory + ((size_t)b * SS + s) * HH + d;
      for (; s + 24 < ihi; s += 32, mp += 32 * HH) {
        const float m0 = mp[0], m1 = mp[8 * HH], m2 = mp[16 * HH], m3 = mp[24 * HH];
        a3 = fmaf(w_s[s - ilo], m0, a3);
        a3 = fmaf(w_s[s + 8 - ilo], m1, a3);
        a3 = fmaf(w_s[s + 16 - ilo], m2, a3);
        a3 = fmaf(w_s[s + 24 - ilo], m3, a3);
      }
      for (; s < ihi; s += 8, mp += 8 * HH) a3 = fmaf(w_s[s - ilo], *mp, a3);
      red2[sg * 68 + dl] = a3;
    }
    __syncthreads();
    if (tid < 64) {
      float cv = 0.f;
#pragma unroll
      for (int g2 = 0; g2 < 8; ++g2) cv += red2[g2 * 68 + tid];
      st_sys(ctx_st + (size_t)b * HH + (pp << 6) + tid, cv);
      const size_t o = ((size_t)b * TT + t) * HH + (pp << 6) + tid;
      out_ctx[o] = cv + input[o];
    }
    if (tid == 0)
      __hip_atomic_store(&bslots[(grp << 5) + rB], seq, __ATOMIC_RELEASE,
                         __HIP_MEMORY_SCOPE_AGENT);

    // ---- stage h(t) (flags already confirmed) + h-part(t+1) ----
    if (t + 1 < TT) {
      {
        f4 hv;
        ld1_sys(h_st + (((size_t)nxt * BB) + B0 + sb) * HH + sk, hv);
        *(f4*)&h_lds[sb * PADR + ski] = hv;
      }
      __syncthreads();
#pragma unroll
      for (int i = 0; i < 4; ++i) {
        const int kx = 20 * ks + 4 * i;
        f4 hb0 = *(const f4*)&h_lds[0 * PADR + kx];
        f4 hb1 = *(const f4*)&h_lds[1 * PADR + kx];
        f4 hb2 = *(const f4*)&h_lds[2 * PADR + kx];
        f4 hb3 = *(const f4*)&h_lds[3 * PADR + kx];
#pragma unroll
        for (int j = 0; j < 4; ++j) {
          uint2 v = *(const uint2*)(whB + (j << 9) + 4 * i);
          f4 wh;
          wh.x = __uint_as_float(v.x << 16); wh.y = __uint_as_float(v.x & 0xffff0000u);
          wh.z = __uint_as_float(v.y << 16); wh.w = __uint_as_float(v.y & 0xffff0000u);
          fma4(acc[j][0], hb0, wh); fma4(acc[j][1], hb1, wh);
          fma4(acc[j][2], hb2, wh); fma4(acc[j][3], hb3, wh);
        }
      }
    }
  }
}

extern "C" void kernel_launch(void* const* d_in, const int* in_sizes, int n_in,
                              void* d_out, int out_size, void* d_ws, size_t ws_size,
                              hipStream_t stream) {
  const float* input = (const float*)d_in[0];
  const float* memory = (const float*)d_in[1];
  const float* Wih = (const float*)d_in[2];
  const float* Whh = (const float*)d_in[3];
  const float* bih = (const float*)d_in[4];
  const float* bhh = (const float*)d_in[5];
  const float* Wg = (const float*)d_in[6];
  const float* bgv = (const float*)d_in[7];
  float* out_ctx = (float*)d_out;
  float* out_align = out_ctx + (size_t)BB * TT * HH;

  char* ws = (char*)d_ws;
  unsigned* slots = (unsigned*)(ws + WS_SLOTS);
  unsigned* aslots = slots;
  unsigned* bslots = slots + 512;
  float* ctx_st = (float*)(ws + WS_CTX);
  float* h_st = (float*)(ws + WS_H);
  unsigned short* Wihb = (unsigned short*)(ws + WS_WIHB);
  unsigned short* Whhb = (unsigned short*)(ws + WS_WHHB);
  unsigned short* Wgb = (unsigned short*)(ws + WS_WGB);
  float* phi_acc = (float*)(ws + WS_PHIA);

  k_init<<<dim3(2048), dim3(256), 0, stream>>>(Wih, Whh, Wg, Wihb, Whhb, Wgb,
                                               out_align, ctx_st, h_st, slots,
                                               phi_acc);

  void* args[] = { (void*)&input, (void*)&memory, (void*)&bih, (void*)&bhh, (void*)&bgv,
                   (void*)&Wihb, (void*)&Whhb, (void*)&Wgb,
                   (void*)&out_ctx, (void*)&out_align,
                   (void*)&ctx_st, (void*)&h_st, (void*)&aslots, (void*)&bslots,
                   (void*)&phi_acc };
  hipLaunchCooperativeKernel((void*)k_main, dim3(256), dim3(512), args, 0, stream);
}

// Round 11
// 8309.877 us; speedup vs baseline: 2.9672x; 1.0383x over previous
//
#include <hip/hip_runtime.h>

#define BB 32
#define TT 512
#define SS 1024
#define HH 512
#define MM 16

typedef float f4 __attribute__((ext_vector_type(4)));

// d_ws layout (bytes)
#define WS_SLOTS  0          // 1024 u32 (512 aslots + 512 bslots)
#define WS_CTX    4096       // 32*512 f32
#define WS_H      69632      // 2*32*512 f32
#define WS_WIHB   200704     // 2048*1024 bf16 (4 MB)
#define WS_WHHB   4395008    // 2048*512 bf16 (2 MB)
#define WS_WGB    6492160    // 48*512 bf16 (48 KB)
#define WS_PHIA   6541312    // 32*48 f32 phi accumulator (single buffer, delta-adds)

#define PADR 640
#define IDXH(k) ((k) + (((k) >> 4) << 2))

__device__ __forceinline__ float sigm(float z) { return 1.f / (1.f + __expf(-z)); }
// stable fast tanh: 1 - 2/(e^{2|x|}+1), sign restored (e overflow -> 1, correct)
__device__ __forceinline__ float tanh_fast(float x) {
  float e = __expf(2.f * fabsf(x));
  return copysignf(1.f - 2.f / (e + 1.f), x);
}
__device__ __forceinline__ float bf2f(unsigned short u) {
  return __uint_as_float((unsigned)u << 16);
}
__device__ __forceinline__ unsigned short f2bf(float f) {
  unsigned u = __float_as_uint(f);
  return (unsigned short)((u + 0x7fffu + ((u >> 16) & 1u)) >> 16);
}
__device__ __forceinline__ void fma4(float& a, const f4& u, const f4& v) {
  a = fmaf(u.x, v.x, fmaf(u.y, v.y, fmaf(u.z, v.z, fmaf(u.w, v.w, a))));
}

// LLC-coherent ops (bypass L1/L2)
__device__ __forceinline__ void ld1_sys(const float* p0, f4& a) {
  asm volatile("global_load_dwordx4 %0, %1, off sc1\n\ts_waitcnt vmcnt(0)"
               : "=&v"(a) : "v"(p0) : "memory");
}
__device__ __forceinline__ void ld1f_sys(const float* p0, float& a) {
  asm volatile("global_load_dword %0, %1, off sc1\n\ts_waitcnt vmcnt(0)"
               : "=&v"(a) : "v"(p0) : "memory");
}
__device__ __forceinline__ void st_sys(float* p, float v) {
  asm volatile("global_store_dword %0, %1, off sc1" :: "v"(p), "v"(v) : "memory");
}

__global__ void k_init(const float* __restrict__ Wih, const float* __restrict__ Whh,
                       const float* __restrict__ Wg,
                       unsigned short* __restrict__ Wihb, unsigned short* __restrict__ Whhb,
                       unsigned short* __restrict__ Wgb,
                       float* __restrict__ out_align, float* __restrict__ ctx_st,
                       float* __restrict__ h_st, unsigned* __restrict__ slots,
                       float* __restrict__ phi_acc) {
  const size_t idx = (size_t)blockIdx.x * blockDim.x + threadIdx.x;
  const size_t stride = (size_t)gridDim.x * blockDim.x;
  f4 z4 = {0.f, 0.f, 0.f, 0.f};
  for (size_t i = idx; i < (size_t)BB * TT * SS / 4; i += stride) ((f4*)out_align)[i] = z4;
  for (size_t i = idx; i < (size_t)BB * HH / 4; i += stride) ((f4*)ctx_st)[i] = z4;
  for (size_t i = idx; i < (size_t)2 * BB * HH / 4; i += stride) ((f4*)h_st)[i] = z4;
  for (size_t i = idx; i < 1024; i += stride) slots[i] = 0u;
  for (size_t i = idx; i < (size_t)BB * 48; i += stride) phi_acc[i] = 0.f;
  for (size_t i = idx; i < (size_t)2048 * 1024; i += stride) Wihb[i] = f2bf(Wih[i]);
  for (size_t i = idx; i < (size_t)2048 * 512; i += stride) Whhb[i] = f2bf(Whh[i]);
  for (size_t i = idx; i < (size_t)48 * 512; i += stride) Wgb[i] = f2bf(Wg[i]);
}

// R10 structure (phi partials via atomics, -12.7%) + R11 changes:
// (1) delta-atomics on a SINGLE phi buffer (no zeroing pass, removes the
//     zero-vs-atomic race margin), (2) whole A-section (poll + phi-read +
//     ksi/beta + softmax + window) fused into ONE wave with in-wave shfl
//     reductions -> 1 barrier instead of 4, (3) fast stable tanh.
__global__ void __launch_bounds__(512, 2)
k_main(const float* __restrict__ input, const float* __restrict__ memory,
       const float* __restrict__ bih, const float* __restrict__ bhh,
       const float* __restrict__ bgv,
       const unsigned short* __restrict__ Wihb,
       const unsigned short* __restrict__ Whhb,
       const unsigned short* __restrict__ Wgb,
       float* __restrict__ out_ctx, float* __restrict__ out_align,
       float* __restrict__ ctx_st, float* __restrict__ h_st,
       unsigned* __restrict__ aslots, unsigned* __restrict__ bslots,
       float* __restrict__ phi_acc) {
  __shared__ float x_lds[4 * PADR];
  __shared__ float c_lds[4 * PADR];
  __shared__ float h_lds[4 * PADR];
  __shared__ float gbuf[16 * 17];
  __shared__ float bias_s[64];
  __shared__ float c_s[64];
  __shared__ float h_sl[64];
  __shared__ float w_s[SS];
  __shared__ float red2[8 * 68];
  __shared__ float alpha_s[MM], rbeta_s[MM], ksi_s[MM];
  __shared__ int win_s[2];

  const int tid = threadIdx.x;
  const int bid = blockIdx.x;
  const int grp = bid >> 5;        // 8 groups of 32 blocks; group owns 4 batches
  const int rB  = bid & 31;        // rank in group -> 16 gate-cols
  const int B0  = grp << 2;

  // phase-A thread coords
  const int ks = tid & 31;
  const int rq = tid >> 5;
  const int gt = rq >> 2;
  const int cq = rq & 3;
  const int colb = (rB << 4) + (cq << 2);
  const unsigned short* wiB = Wihb + (((size_t)(gt << 9) + colb) << 10) + (ks << 4);
  const unsigned short* whB = Whhb + (((size_t)(gt << 9) + colb) << 9) + (ks << 4);

  // phase-B coords: 8 blocks per batch
  const int bq = rB >> 3;
  const int pp = rB & 7;
  const int b  = B0 + bq;

  // staging coords
  const int sb = tid >> 7;
  const int sk = (tid & 127) << 2;
  const int ski = IDXH(sk);

  if (tid < 64) {
    const int row = ((tid >> 4) << 9) + (rB << 4) + (tid & 15);
    bias_s[tid] = bih[row] + bhh[row];
    c_s[tid] = 0.f;
  }
  if (tid < MM) ksi_s[tid] = 0.f;
  __syncthreads();

  float acc[4][4];
  float prev_pa[3] = {0.f, 0.f, 0.f};   // delta-atomic memory (LSTM wave only)

  // ---- prologue: stage x(0), h(-1)=0; compute x+h parts for t=0 ----
  {
    f4 xv = *(const f4*)(input + ((size_t)(B0 + sb) * TT + 0) * HH + sk);
    f4 hv;
    ld1_sys(h_st + (size_t)(B0 + sb) * HH + sk, hv);
    *(f4*)&x_lds[sb * PADR + ski] = xv;
    *(f4*)&h_lds[sb * PADR + ski] = hv;
  }
  __syncthreads();
#pragma unroll
  for (int j = 0; j < 4; ++j)
#pragma unroll
    for (int b2 = 0; b2 < 4; ++b2) acc[j][b2] = 0.f;
#pragma unroll
  for (int i = 0; i < 4; ++i) {
    const int kx = 20 * ks + 4 * i;
    f4 xb0 = *(const f4*)&x_lds[0 * PADR + kx];
    f4 xb1 = *(const f4*)&x_lds[1 * PADR + kx];
    f4 xb2 = *(const f4*)&x_lds[2 * PADR + kx];
    f4 xb3 = *(const f4*)&x_lds[3 * PADR + kx];
    f4 hb0 = *(const f4*)&h_lds[0 * PADR + kx];
    f4 hb1 = *(const f4*)&h_lds[1 * PADR + kx];
    f4 hb2 = *(const f4*)&h_lds[2 * PADR + kx];
    f4 hb3 = *(const f4*)&h_lds[3 * PADR + kx];
#pragma unroll
    for (int j = 0; j < 4; ++j) {
      uint2 u = *(const uint2*)(wiB + (j << 10) + 4 * i);
      f4 wf;
      wf.x = __uint_as_float(u.x << 16); wf.y = __uint_as_float(u.x & 0xffff0000u);
      wf.z = __uint_as_float(u.y << 16); wf.w = __uint_as_float(u.y & 0xffff0000u);
      fma4(acc[j][0], xb0, wf); fma4(acc[j][1], xb1, wf);
      fma4(acc[j][2], xb2, wf); fma4(acc[j][3], xb3, wf);
      uint2 v = *(const uint2*)(whB + (j << 9) + 4 * i);
      f4 wh;
      wh.x = __uint_as_float(v.x << 16); wh.y = __uint_as_float(v.x & 0xffff0000u);
      wh.z = __uint_as_float(v.y << 16); wh.w = __uint_as_float(v.y & 0xffff0000u);
      fma4(acc[j][0], hb0, wh); fma4(acc[j][1], hb1, wh);
      fma4(acc[j][2], hb2, wh); fma4(acc[j][3], hb3, wh);
    }
  }

  for (int t = 0; t < TT; ++t) {
    const unsigned seq = (unsigned)(t + 1);
    const int nxt = (t + 1) & 1;

    // ---- wait ctx(t-1) ready, stage it ----
    if (tid < 32) {
      while (__hip_atomic_load(&bslots[(grp << 5) + tid], __ATOMIC_RELAXED,
                               __HIP_MEMORY_SCOPE_AGENT) < (unsigned)t) {}
    }
    __syncthreads();
    {
      f4 cv;
      ld1_sys(ctx_st + (size_t)(B0 + sb) * HH + sk, cv);
      *(f4*)&c_lds[sb * PADR + ski] = cv;
    }
    __syncthreads();

    // ---- ctx-part of gates(t) ----
#pragma unroll
    for (int i = 0; i < 4; ++i) {
      const int kx = 20 * ks + 4 * i;
      f4 cb0 = *(const f4*)&c_lds[0 * PADR + kx];
      f4 cb1 = *(const f4*)&c_lds[1 * PADR + kx];
      f4 cb2 = *(const f4*)&c_lds[2 * PADR + kx];
      f4 cb3 = *(const f4*)&c_lds[3 * PADR + kx];
#pragma unroll
      for (int j = 0; j < 4; ++j) {
        uint2 u = *(const uint2*)(wiB + 512 + (j << 10) + 4 * i);
        f4 wf;
        wf.x = __uint_as_float(u.x << 16); wf.y = __uint_as_float(u.x & 0xffff0000u);
        wf.z = __uint_as_float(u.y << 16); wf.w = __uint_as_float(u.y & 0xffff0000u);
        fma4(acc[j][0], cb0, wf); fma4(acc[j][1], cb1, wf);
        fma4(acc[j][2], cb2, wf); fma4(acc[j][3], cb3, wf);
      }
    }
    // ---- reduce over ks ----
#pragma unroll
    for (int j = 0; j < 4; ++j)
#pragma unroll
      for (int b2 = 0; b2 < 4; ++b2) {
        float v = acc[j][b2];
        v += __shfl_xor(v, 1, 64);
        v += __shfl_xor(v, 2, 64);
        v += __shfl_xor(v, 4, 64);
        v += __shfl_xor(v, 8, 64);
        v += __shfl_xor(v, 16, 64);
        acc[j][b2] = v;
      }
    if ((tid & 31) == 0) {
#pragma unroll
      for (int j = 0; j < 4; ++j)
#pragma unroll
        for (int b2 = 0; b2 < 4; ++b2)
          gbuf[((b2 << 2) + gt) * 17 + (cq << 2) + j] = acc[j][b2];
    }
    __syncthreads();
    // ---- LSTM cell + publish h(t) + phi delta-partials + flag A ----
    if (tid < 64) {
      const int b2 = tid >> 4, cl = tid & 15;
      const float ig = gbuf[((b2 << 2) + 0) * 17 + cl] + bias_s[cl];
      const float fg = gbuf[((b2 << 2) + 1) * 17 + cl] + bias_s[16 + cl];
      const float gg = gbuf[((b2 << 2) + 2) * 17 + cl] + bias_s[32 + cl];
      const float og = gbuf[((b2 << 2) + 3) * 17 + cl] + bias_s[48 + cl];
      float c = sigm(fg) * c_s[tid] + sigm(ig) * tanh_fast(gg);
      c_s[tid] = c;
      const float h = sigm(og) * tanh_fast(c);
      h_sl[tid] = h;
      st_sys(h_st + (((size_t)nxt * BB) + B0 + b2) * HH + (rB << 4) + cl, h);
      // phi delta-partials: 3 (batch,row) pairs per lane (192 = 4 x 48)
#pragma unroll
      for (int q = 0; q < 3; ++q) {
        const int e = q * 64 + tid;
        const int bp = e / 48, r2 = e % 48;
        const unsigned short* wr = Wgb + (r2 << 9) + (rB << 4);
        float pa = 0.f;
#pragma unroll
        for (int c2 = 0; c2 < 4; ++c2) {
          uint2 u = *(const uint2*)(wr + (c2 << 2));
          const float* hb = &h_sl[(bp << 4) + (c2 << 2)];
          pa = fmaf(__uint_as_float(u.x << 16), hb[0], pa);
          pa = fmaf(__uint_as_float(u.x & 0xffff0000u), hb[1], pa);
          pa = fmaf(__uint_as_float(u.y << 16), hb[2], pa);
          pa = fmaf(__uint_as_float(u.y & 0xffff0000u), hb[3], pa);
        }
        const float d = pa - prev_pa[q];
        prev_pa[q] = pa;
        __hip_atomic_fetch_add(phi_acc + (size_t)(B0 + bp) * 48 + r2,
                               d, __ATOMIC_RELAXED, __HIP_MEMORY_SCOPE_AGENT);
      }
    }
    if (tid == 0)
      __hip_atomic_store(&aslots[(grp << 5) + rB], seq, __ATOMIC_RELEASE,
                         __HIP_MEMORY_SCOPE_AGENT);

    // ---- stage x(t+1) + compute x-part(t+1) ----
    {
      const int tload = (t + 1 < TT) ? (t + 1) : t;
      f4 xv = *(const f4*)(input + ((size_t)(B0 + sb) * TT + tload) * HH + sk);
      *(f4*)&x_lds[sb * PADR + ski] = xv;
    }
    __syncthreads();
#pragma unroll
    for (int j = 0; j < 4; ++j)
#pragma unroll
      for (int b2 = 0; b2 < 4; ++b2) acc[j][b2] = 0.f;
#pragma unroll
    for (int i = 0; i < 4; ++i) {
      const int kx = 20 * ks + 4 * i;
      f4 xb0 = *(const f4*)&x_lds[0 * PADR + kx];
      f4 xb1 = *(const f4*)&x_lds[1 * PADR + kx];
      f4 xb2 = *(const f4*)&x_lds[2 * PADR + kx];
      f4 xb3 = *(const f4*)&x_lds[3 * PADR + kx];
#pragma unroll
      for (int j = 0; j < 4; ++j) {
        uint2 u = *(const uint2*)(wiB + (j << 10) + 4 * i);
        f4 wf;
        wf.x = __uint_as_float(u.x << 16); wf.y = __uint_as_float(u.x & 0xffff0000u);
        wf.z = __uint_as_float(u.y << 16); wf.w = __uint_as_float(u.y & 0xffff0000u);
        fma4(acc[j][0], xb0, wf); fma4(acc[j][1], xb1, wf);
        fma4(acc[j][2], xb2, wf); fma4(acc[j][3], xb3, wf);
      }
    }

    // ---- fused A-section (one wave): poll -> phi read -> softmax -> window
    if (tid < 64) {
      if (tid < 32) {
        while (__hip_atomic_load(&aslots[(grp << 5) + tid], __ATOMIC_RELAXED,
                                 __HIP_MEMORY_SCOPE_AGENT) < seq) {}
      }
      float pv = 0.f;
      if (tid < 48) {
        ld1f_sys(phi_acc + (size_t)b * 48 + tid, pv);
        pv += bgv[tid];
      }
      const int m = tid & 15;
      const float pb = __shfl(pv, 16 + m, 64);   // phi_beta row m
      const float pc = __shfl(pv, 32 + m, 64);   // phi_alpha row m
      if (tid < 16) {
        const float ksn = ksi_s[m] + __expf(pv); // pv = phi_ksi row m
        ksi_s[m] = ksn;
        const float bt = __expf(pb);
        rbeta_s[m] = 1.f / bt;
        // softmax over lanes 0-15
        float mx = pc;
        mx = fmaxf(mx, __shfl_xor(mx, 8, 64));
        mx = fmaxf(mx, __shfl_xor(mx, 4, 64));
        mx = fmaxf(mx, __shfl_xor(mx, 2, 64));
        mx = fmaxf(mx, __shfl_xor(mx, 1, 64));
        const float ev = __expf(pc - mx);
        float sm = ev;
        sm += __shfl_xor(sm, 8, 64);
        sm += __shfl_xor(sm, 4, 64);
        sm += __shfl_xor(sm, 2, 64);
        sm += __shfl_xor(sm, 1, 64);
        alpha_s[m] = ev / sm;
        const float dd = 13.f * bt + 3.f;
        float lo = ksn - dd, hi = ksn + dd;
        lo = fminf(lo, __shfl_xor(lo, 8, 64)); hi = fmaxf(hi, __shfl_xor(hi, 8, 64));
        lo = fminf(lo, __shfl_xor(lo, 4, 64)); hi = fmaxf(hi, __shfl_xor(hi, 4, 64));
        lo = fminf(lo, __shfl_xor(lo, 2, 64)); hi = fmaxf(hi, __shfl_xor(hi, 2, 64));
        lo = fminf(lo, __shfl_xor(lo, 1, 64)); hi = fmaxf(hi, __shfl_xor(hi, 1, 64));
        if (tid == 0) {
          int ilo = (int)floorf(lo); if (ilo < 0) ilo = 0; if (ilo > SS) ilo = SS;
          int ihi = (int)ceilf(hi) + 1; if (ihi > SS) ihi = SS; if (ihi < ilo) ihi = ilo;
          win_s[0] = ilo; win_s[1] = ihi;
        }
      }
    }
    __syncthreads();
    const int ilo = win_s[0], ihi = win_s[1];
    {
      float* arow = out_align + ((size_t)b * TT + t) * SS;
      for (int s = ilo + tid; s < ihi; s += 512) {
        const float us = (float)s;
        float wsum = 0.f;
#pragma unroll
        for (int m2 = 0; m2 < MM; ++m2) {
          const float rb2 = rbeta_s[m2];
          const float z1 = (us + 1.5f - ksi_s[m2]) * rb2;
          const float z0 = (us + 0.5f - ksi_s[m2]) * rb2;
          wsum += alpha_s[m2] * (sigm(z1) - sigm(z0));
        }
        w_s[s - ilo] = wsum;
        if (pp == 0) arow[s] = wsum;
      }
    }
    __syncthreads();
    {
      const int dl = tid & 63, sg = tid >> 6;
      const int d = (pp << 6) + dl;
      float a3 = 0.f;
      int s = ilo + sg;
      const float* mp = memory + ((size_t)b * SS + s) * HH + d;
      for (; s + 24 < ihi; s += 32, mp += 32 * HH) {
        const float m0 = mp[0], m1 = mp[8 * HH], m2 = mp[16 * HH], m3 = mp[24 * HH];
        a3 = fmaf(w_s[s - ilo], m0, a3);
        a3 = fmaf(w_s[s + 8 - ilo], m1, a3);
        a3 = fmaf(w_s[s + 16 - ilo], m2, a3);
        a3 = fmaf(w_s[s + 24 - ilo], m3, a3);
      }
      for (; s < ihi; s += 8, mp += 8 * HH) a3 = fmaf(w_s[s - ilo], *mp, a3);
      red2[sg * 68 + dl] = a3;
    }
    __syncthreads();
    if (tid < 64) {
      float cv = 0.f;
#pragma unroll
      for (int g2 = 0; g2 < 8; ++g2) cv += red2[g2 * 68 + tid];
      st_sys(ctx_st + (size_t)b * HH + (pp << 6) + tid, cv);
      const size_t o = ((size_t)b * TT + t) * HH + (pp << 6) + tid;
      out_ctx[o] = cv + input[o];
    }
    if (tid == 0)
      __hip_atomic_store(&bslots[(grp << 5) + rB], seq, __ATOMIC_RELEASE,
                         __HIP_MEMORY_SCOPE_AGENT);

    // ---- stage h(t) (A-wait already passed) + h-part(t+1) ----
    if (t + 1 < TT) {
      {
        f4 hv;
        ld1_sys(h_st + (((size_t)nxt * BB) + B0 + sb) * HH + sk, hv);
        *(f4*)&h_lds[sb * PADR + ski] = hv;
      }
      __syncthreads();
#pragma unroll
      for (int i = 0; i < 4; ++i) {
        const int kx = 20 * ks + 4 * i;
        f4 hb0 = *(const f4*)&h_lds[0 * PADR + kx];
        f4 hb1 = *(const f4*)&h_lds[1 * PADR + kx];
        f4 hb2 = *(const f4*)&h_lds[2 * PADR + kx];
        f4 hb3 = *(const f4*)&h_lds[3 * PADR + kx];
#pragma unroll
        for (int j = 0; j < 4; ++j) {
          uint2 v = *(const uint2*)(whB + (j << 9) + 4 * i);
          f4 wh;
          wh.x = __uint_as_float(v.x << 16); wh.y = __uint_as_float(v.x & 0xffff0000u);
          wh.z = __uint_as_float(v.y << 16); wh.w = __uint_as_float(v.y & 0xffff0000u);
          fma4(acc[j][0], hb0, wh); fma4(acc[j][1], hb1, wh);
          fma4(acc[j][2], hb2, wh); fma4(acc[j][3], hb3, wh);
        }
      }
    }
  }
}

extern "C" void kernel_launch(void* const* d_in, const int* in_sizes, int n_in,
                              void* d_out, int out_size, void* d_ws, size_t ws_size,
                              hipStream_t stream) {
  const float* input = (const float*)d_in[0];
  const float* memory = (const float*)d_in[1];
  const float* Wih = (const float*)d_in[2];
  const float* Whh = (const float*)d_in[3];
  const float* bih = (const float*)d_in[4];
  const float* bhh = (const float*)d_in[5];
  const float* Wg = (const float*)d_in[6];
  const float* bgv = (const float*)d_in[7];
  float* out_ctx = (float*)d_out;
  float* out_align = out_ctx + (size_t)BB * TT * HH;

  char* ws = (char*)d_ws;
  unsigned* slots = (unsigned*)(ws + WS_SLOTS);
  unsigned* aslots = slots;
  unsigned* bslots = slots + 512;
  float* ctx_st = (float*)(ws + WS_CTX);
  float* h_st = (float*)(ws + WS_H);
  unsigned short* Wihb = (unsigned short*)(ws + WS_WIHB);
  unsigned short* Whhb = (unsigned short*)(ws + WS_WHHB);
  unsigned short* Wgb = (unsigned short*)(ws + WS_WGB);
  float* phi_acc = (float*)(ws + WS_PHIA);

  k_init<<<dim3(2048), dim3(256), 0, stream>>>(Wih, Whh, Wg, Wihb, Whhb, Wgb,
                                               out_align, ctx_st, h_st, slots,
                                               phi_acc);

  void* args[] = { (void*)&input, (void*)&memory, (void*)&bih, (void*)&bhh, (void*)&bgv,
                   (void*)&Wihb, (void*)&Whhb, (void*)&Wgb,
                   (void*)&out_ctx, (void*)&out_align,
                   (void*)&ctx_st, (void*)&h_st, (void*)&aslots, (void*)&bslots,
                   (void*)&phi_acc };
  hipLaunchCooperativeKernel((void*)k_main, dim3(256), dim3(512), args, 0, stream);
}